// Round 13
// baseline (50.626 us; speedup 1.0000x reference)
//
#include <hip/hip_runtime.h>
#include <hip/hip_bf16.h>
#include <stdint.h>

// out[b,o,p] = sum_{r,c} mat0[b,c,p] * mat1[o,c,r]*Alpha[r] * mask[r,p]
// GEMM: M=256 (o), N=32768 (n=b*4096+p), K=2048 (k=c*8+r).
// A[o,k] = mat1[o,c,r]*Alpha[r]  (prepped FP16 in d_ws, layout [c][o][8r])
// B[k,n] = mat0[b,c,p]*mask[r,p] synthesized IN REGISTERS per lane (fp16).
// Round 13: ANTI-LOCKSTEP. One 32x32 MFMA = 32 cyc on its SIMD pipe; the 2
// waves/SIMD (same wave-slot of the 2 co-resident blocks) ran identical
// barrier-locked schedules -> MFMA clusters collide (pipe queues, no loads
// issued), then both stall on vmcnt together (pipe idle) -> pipes serialize
// (3255 cyc/round vs ~1100 ideal). Fix: (1) 4-slab ring, ONE barrier per 2
// rounds (free-run windows, per-wave vmcnt(0) on 2-round-old loads);
// (2) kq-rotation by block parity (static dual code path) so co-resident
// blocks interleave MFMA clusters; (3) setprio around clusters (T5 regime).

typedef __attribute__((ext_vector_type(8)))  _Float16 half8;
typedef __attribute__((ext_vector_type(16))) float    f32x16;

#define C_IN  256
#define HW_   4096
#define NRND  32    // K rounds of 64 (8 c-planes per round)

__global__ __launch_bounds__(256) void prep_w_kernel(
    const float* __restrict__ mat1, const float* __restrict__ Alpha,
    const int* __restrict__ use_alpha, _Float16* __restrict__ Aprep) {
  int t = blockIdx.x * 256 + threadIdx.x;   // o = t&255, c = t>>8
  int o = t & 255;
  int c = t >> 8;
  int ua = use_alpha[0];
  const float* src = mat1 + ((size_t)o * C_IN + c) * 8;
  half8 v;
#pragma unroll
  for (int r = 0; r < 8; ++r) {
    float s = ua ? Alpha[r] : 1.0f;
    v[r] = (_Float16)(src[r] * s);
  }
  // layout: slot (c*256 + o) holds 8 fp16 (r fastest)
  *(half8*)(Aprep + ((size_t)c * 256 + o) * 8) = v;
}

__global__ __launch_bounds__(256, 2) void gemm_deform_kernel(
    const float* __restrict__ mat0, const _Float16* __restrict__ Aprep,
    const float* __restrict__ mask, float* __restrict__ out) {
  // 4-slab ring: slab s holds round rd (rd%4==s): 8 c-planes x 128 rows
  __shared__ half8 A_lds[4][1024];   // 64 KiB

  int bid = blockIdx.x;
  int wg = (bid & 7) * 64 + (bid >> 3);   // XCD swizzle (512%8==0, bijective)
  int tile_m = wg & 1;                    // M fastest: pair shares mat0 cols
  int tile_n = wg >> 1;                   // 0..255
  int o0 = tile_m * 128;
  int n0 = tile_n * 128;
  int b  = n0 >> 12;
  int p0 = n0 & 4095;

  int t    = threadIdx.x;
  int lane = t & 63;
  int w    = t >> 6;        // 0..3
  int wc   = w & 1;         // N-half (64 cols)
  int wr   = w >> 1;        // M-half (64 rows)
  int l31  = lane & 31;
  int cr   = lane >> 5;     // c-plane parity within MFMA K=16

  // this wave's two 32-col groups; lane-resident packed fp16 mask
  int colb = p0 + wc * 64 + l31;
  half8 mkh[2];
#pragma unroll
  for (int ni = 0; ni < 2; ++ni)
#pragma unroll
    for (int r = 0; r < 8; ++r)
      mkh[ni][r] = (_Float16)mask[r * HW_ + colb + ni * 32];

  // mat0 scalar source: plane c = rd*8 + kq*2 + cr, columns colb, colb+32
  const float* __restrict__ m0b =
      mat0 + ((size_t)b * C_IN + cr) * HW_ + colb;

  // A staging: global slot (16B units) in Aprep; LDS dest wave-uniform base
  const __attribute__((address_space(1))) uint32_t* gA =
      (const __attribute__((address_space(1))) uint32_t*)Aprep;
  __attribute__((address_space(3))) uint32_t* lA =
      (__attribute__((address_space(3))) uint32_t*)&A_lds[0][0];
  int soo  = (w & 1) * 64 + lane;   // column part of this thread's src slot
  int scqb = w >> 1;                // c-plane parity of this thread's src slot

  f32x16 acc[2][2];   // [mi][ni]
#pragma unroll
  for (int mi = 0; mi < 2; ++mi)
#pragma unroll
    for (int ni = 0; ni < 2; ++ni)
#pragma unroll
      for (int j = 0; j < 16; ++j) acc[mi][ni][j] = 0.f;

  float PA[4][2], PB[4][2], PC[4][2], PD[4][2];   // P sets, ping-pong per super

  auto STAGE = [&](int rd, int s) {   // 4 global_load_lds into slab s
#pragma unroll
    for (int i = 0; i < 4; ++i) {
      int gslot = (rd * 8 + i * 2 + scqb) * 256 + o0 + soo;
      __builtin_amdgcn_global_load_lds(gA + (size_t)gslot * 4,
                                       lA + (size_t)(s * 1024 + i * 256 + w * 64) * 4,
                                       16, 0, 0);
    }
  };

  auto LOADP = [&](float (&P)[4][2], int rd) {   // 8 scalar loads
    const float* mp = m0b + (size_t)(rd * 8) * HW_;
#pragma unroll
    for (int kq = 0; kq < 4; ++kq) {
      P[kq][0] = mp[(size_t)(kq * 2) * HW_];
      P[kq][1] = mp[(size_t)(kq * 2) * HW_ + 32];
    }
  };

#define KQ_STEP(KQ) do {                                                      \
    half8 a0 = Abuf[((KQ) * 2 + cr) * 128 + wr * 64 + l31];                   \
    half8 a1 = Abuf[((KQ) * 2 + cr) * 128 + wr * 64 + 32 + l31];              \
    _Float16 h0 = (_Float16)P[KQ][0];                                         \
    _Float16 h1 = (_Float16)P[KQ][1];                                         \
    half8 pb0 = {h0, h0, h0, h0, h0, h0, h0, h0};                             \
    half8 pb1 = {h1, h1, h1, h1, h1, h1, h1, h1};                             \
    half8 bv0 = pb0 * mkh[0];                                                 \
    half8 bv1 = pb1 * mkh[1];                                                 \
    __builtin_amdgcn_s_setprio(1);                                            \
    acc[0][0] = __builtin_amdgcn_mfma_f32_32x32x16_f16(a0, bv0, acc[0][0], 0, 0, 0); \
    acc[0][1] = __builtin_amdgcn_mfma_f32_32x32x16_f16(a0, bv1, acc[0][1], 0, 0, 0); \
    acc[1][0] = __builtin_amdgcn_mfma_f32_32x32x16_f16(a1, bv0, acc[1][0], 0, 0, 0); \
    acc[1][1] = __builtin_amdgcn_mfma_f32_32x32x16_f16(a1, bv1, acc[1][1], 0, 0, 0); \
    __builtin_amdgcn_s_setprio(0);                                            \
  } while (0)

  auto comp0 = [&](const half8* __restrict__ Abuf, const float (&P)[4][2]) {
    KQ_STEP(0); KQ_STEP(1); KQ_STEP(2); KQ_STEP(3);
  };
  auto comp2 = [&](const half8* __restrict__ Abuf, const float (&P)[4][2]) {
    KQ_STEP(2); KQ_STEP(3); KQ_STEP(0); KQ_STEP(1);
  };

  const half8* __restrict__ slab0 = &A_lds[0][0];
  const half8* __restrict__ slab1 = &A_lds[1][0];
  const half8* __restrict__ slab2 = &A_lds[2][0];
  const half8* __restrict__ slab3 = &A_lds[3][0];

  // ---- prologue: rounds 0,1 staged; P(0),P(1) loaded ----
  STAGE(0, 0); STAGE(1, 1);
  LOADP(PA, 0); LOADP(PB, 1);

  // Per super (2 rounds): vmcnt(0) on 2-round-old loads (cheap), one
  // barrier (slab-overwrite safety), issue next stage+P, two COMP rounds.
#define MAIN_LOOP(COMPF)                                                      \
  _Pragma("unroll 1")                                                         \
  for (int i = 0; i < 8; ++i) {                                               \
    int r0 = i * 4;                                                           \
    /* super A: compute r0, r0+1 (slabs 0,1); stage r0+2,r0+3 (slabs 2,3) */  \
    asm volatile("s_waitcnt vmcnt(0)" ::: "memory");                          \
    __builtin_amdgcn_s_barrier();                                             \
    STAGE(r0 + 2, 2); STAGE(r0 + 3, 3);                                       \
    LOADP(PC, r0 + 2); LOADP(PD, r0 + 3);                                     \
    COMPF(slab0, PA); COMPF(slab1, PB);                                       \
    /* super B: compute r0+2, r0+3 (slabs 2,3); stage r0+4,r0+5 (slabs 0,1) */\
    asm volatile("s_waitcnt vmcnt(0)" ::: "memory");                          \
    __builtin_amdgcn_s_barrier();                                             \
    {                                                                         \
      int r4 = r0 + 4 > 31 ? 31 : r0 + 4;   /* tail: dummy restage */         \
      int r5 = r0 + 5 > 31 ? 31 : r0 + 5;                                     \
      STAGE(r4, 0); STAGE(r5, 1);                                             \
      LOADP(PA, r4); LOADP(PB, r5);                                           \
    }                                                                         \
    COMPF(slab2, PC); COMPF(slab3, PD);                                       \
  }

  if (bid & 1) { MAIN_LOOP(comp2) } else { MAIN_LOOP(comp0) }

  // ---- epilogue: 32x32 C/D layout col=lane&31, row=(reg&3)+8*(reg>>2)+4*cr ----
  size_t obase = (size_t)b * 256 * HW_ + colb;
#pragma unroll
  for (int mi = 0; mi < 2; ++mi) {
#pragma unroll
    for (int ni = 0; ni < 2; ++ni) {
#pragma unroll
      for (int reg = 0; reg < 16; ++reg) {
        int row = o0 + wr * 64 + mi * 32 + (reg & 3) + 8 * (reg >> 2) + 4 * cr;
        out[obase + (size_t)row * HW_ + ni * 32] = acc[mi][ni][reg];
      }
    }
  }
}

extern "C" void kernel_launch(void* const* d_in, const int* in_sizes, int n_in,
                              void* d_out, int out_size, void* d_ws, size_t ws_size,
                              hipStream_t stream) {
  const float* mat0      = (const float*)d_in[0];   // [8,256,64,64]
  const float* mat1      = (const float*)d_in[1];   // [256,256,8]
  const float* mask      = (const float*)d_in[2];   // [8,64,64]
  const float* Alpha     = (const float*)d_in[3];   // [8]
  const int*   use_alpha = (const int*)d_in[4];     // [1]
  (void)in_sizes; (void)n_in; (void)out_size; (void)ws_size;

  _Float16* Aprep = (_Float16*)d_ws;                // 1 MiB scratch
  float* outp  = (float*)d_out;

  prep_w_kernel<<<256, 256, 0, stream>>>(mat1, Alpha, use_alpha, Aprep);
  gemm_deform_kernel<<<512, 256, 0, stream>>>(mat0, Aprep, mask, outp);
}

// Round 14
// 47.980 us; speedup vs baseline: 1.0551x; 1.0551x over previous
//
#include <hip/hip_runtime.h>
#include <hip/hip_bf16.h>
#include <stdint.h>

// out[b,o,p] = sum_{r,c} mat0[b,c,p] * mat1[o,c,r]*Alpha[r] * mask[r,p]
// GEMM: M=256 (o), N=32768 (n=b*4096+p), K=2048 (k=c*8+r).
// A[o,k] = mat1[o,c,r]*Alpha[r]  (prepped FP16 in d_ws, layout [c][o][8r])
// B[k,n] = mat0[b,c,p]*mask[r,p] synthesized IN REGISTERS per lane (fp16).
// Round 14 = R12 macro-structure + three surgical fixes:
//  (1) pointer-bump addressing: P/stage addresses held in VGPR pointers,
//      bumped once per round (SALU-selected clamp keeps vmcnt counts exact)
//      -> kills the ~740 cyc/SIMD-round of 64-bit address VALU (PMC: 22%
//      VALUBusy was ~3x the synth cost).
//  (2) read-ahead COMP: ds_read kq+1's a-pair before kq's MFMA quad ->
//      covers the per-kq lgkmcnt exposure.
//  (3) 4-slab ring, stage-pair after each even-round barrier -> 16 barriers
//      total, one vmcnt(0)-on-old per 2 rounds.

typedef __attribute__((ext_vector_type(8)))  _Float16 half8;
typedef __attribute__((ext_vector_type(16))) float    f32x16;

#define C_IN  256
#define HW_   4096
#define NRND  32    // K rounds of 64 (8 c-planes per round)

__global__ __launch_bounds__(256) void prep_w_kernel(
    const float* __restrict__ mat1, const float* __restrict__ Alpha,
    const int* __restrict__ use_alpha, _Float16* __restrict__ Aprep) {
  int t = blockIdx.x * 256 + threadIdx.x;   // o = t&255, c = t>>8
  int o = t & 255;
  int c = t >> 8;
  int ua = use_alpha[0];
  const float* src = mat1 + ((size_t)o * C_IN + c) * 8;
  half8 v;
#pragma unroll
  for (int r = 0; r < 8; ++r) {
    float s = ua ? Alpha[r] : 1.0f;
    v[r] = (_Float16)(src[r] * s);
  }
  // layout: slot (c*256 + o) holds 8 fp16 (r fastest)
  *(half8*)(Aprep + ((size_t)c * 256 + o) * 8) = v;
}

__global__ __launch_bounds__(256, 2) void gemm_deform_kernel(
    const float* __restrict__ mat0, const _Float16* __restrict__ Aprep,
    const float* __restrict__ mask, float* __restrict__ out) {
  // slab = one round: 8 c-planes x 128 rows, slot = cq*128 + (o-o0), 16B
  __shared__ half8 A_lds[4][1024];   // 64 KiB, 4-slab ring (slab = rd%4)

  int bid = blockIdx.x;
  int wg = (bid & 7) * 64 + (bid >> 3);   // XCD swizzle (512%8==0, bijective)
  int tile_m = wg & 1;                    // M fastest: pair shares mat0 cols
  int tile_n = wg >> 1;                   // 0..255
  int o0 = tile_m * 128;
  int n0 = tile_n * 128;
  int b  = n0 >> 12;
  int p0 = n0 & 4095;

  int t    = threadIdx.x;
  int lane = t & 63;
  int w    = t >> 6;        // 0..3
  int wc   = w & 1;         // N-half (64 cols)
  int wr   = w >> 1;        // M-half (64 rows)
  int l31  = lane & 31;
  int cr   = lane >> 5;     // c-plane parity within MFMA K=16

  // lane-resident packed fp16 mask for this wave's two 32-col groups
  int colb = p0 + wc * 64 + l31;
  half8 mkh0, mkh1;
#pragma unroll
  for (int r = 0; r < 8; ++r) {
    mkh0[r] = (_Float16)mask[r * HW_ + colb];
    mkh1[r] = (_Float16)mask[r * HW_ + colb + 32];
  }

  // mat0 scalar base: plane c = rd*8 + kq*2 + cr, columns colb / colb+32
  const float* __restrict__ m0b =
      mat0 + ((size_t)b * C_IN + cr) * HW_ + colb;

  // ---- pointer-bump state ----
  const __attribute__((address_space(1))) uint32_t* gA =
      (const __attribute__((address_space(1))) uint32_t*)Aprep;
  __attribute__((address_space(3))) uint32_t* lA =
      (__attribute__((address_space(3))) uint32_t*)&A_lds[0][0];
  int soo  = (w & 1) * 64 + lane;
  int scqb = w >> 1;
  // stage pointers i=0..3 (dword units); advance 8192 dwords (32KB) / round
  const __attribute__((address_space(1))) uint32_t* gS0 =
      gA + (size_t)((0 * 2 + scqb) * 256 + o0 + soo) * 4;
  const __attribute__((address_space(1))) uint32_t* gS1 =
      gA + (size_t)((1 * 2 + scqb) * 256 + o0 + soo) * 4;
  const __attribute__((address_space(1))) uint32_t* gS2 =
      gA + (size_t)((2 * 2 + scqb) * 256 + o0 + soo) * 4;
  const __attribute__((address_space(1))) uint32_t* gS3 =
      gA + (size_t)((3 * 2 + scqb) * 256 + o0 + soo) * 4;
  // P pointers kq=0..3; advance 8*HW_ floats (128KB) / round
  const float* pP0 = m0b + (size_t)0 * HW_;
  const float* pP1 = m0b + (size_t)2 * HW_;
  const float* pP2 = m0b + (size_t)4 * HW_;
  const float* pP3 = m0b + (size_t)6 * HW_;

#define STAGE(SLAB, SB) do {                                                  \
    __builtin_amdgcn_global_load_lds(gS0, lA + ((SLAB)*1024 + 0*256 + w*64)*4, 16, 0, 0); \
    __builtin_amdgcn_global_load_lds(gS1, lA + ((SLAB)*1024 + 1*256 + w*64)*4, 16, 0, 0); \
    __builtin_amdgcn_global_load_lds(gS2, lA + ((SLAB)*1024 + 2*256 + w*64)*4, 16, 0, 0); \
    __builtin_amdgcn_global_load_lds(gS3, lA + ((SLAB)*1024 + 3*256 + w*64)*4, 16, 0, 0); \
    gS0 += (SB); gS1 += (SB); gS2 += (SB); gS3 += (SB);                       \
  } while (0)

  f32x16 acc00, acc01, acc10, acc11;
#pragma unroll
  for (int j = 0; j < 16; ++j) { acc00[j] = 0.f; acc01[j] = 0.f; acc10[j] = 0.f; acc11[j] = 0.f; }

  float Pev[4][2], Pod[4][2];   // P sets for even / odd rounds

  auto SM = [&](float s0, float s1, half8 A0, half8 A1) {
    _Float16 h0 = (_Float16)s0, h1 = (_Float16)s1;
    half8 pb0 = {h0, h0, h0, h0, h0, h0, h0, h0};
    half8 pb1 = {h1, h1, h1, h1, h1, h1, h1, h1};
    half8 bv0 = pb0 * mkh0;   // 4x v_pk_mul_f16
    half8 bv1 = pb1 * mkh1;
    acc00 = __builtin_amdgcn_mfma_f32_32x32x16_f16(A0, bv0, acc00, 0, 0, 0);
    acc01 = __builtin_amdgcn_mfma_f32_32x32x16_f16(A0, bv1, acc01, 0, 0, 0);
    acc10 = __builtin_amdgcn_mfma_f32_32x32x16_f16(A1, bv0, acc10, 0, 0, 0);
    acc11 = __builtin_amdgcn_mfma_f32_32x32x16_f16(A1, bv1, acc11, 0, 0, 0);
  };

  int abase = wr * 64 + l31;   // + (kq*2+cr)*128 (+32 for second frag)

  // COMP one round from slab Ab using P set; refills P (next-next round), PB clamp
  auto COMP = [&](const half8* __restrict__ Ab, float (&P)[4][2], int PB) {
    half8 a0 = Ab[(0 + cr) * 128 + abase];
    half8 a1 = Ab[(0 + cr) * 128 + abase + 32];
    // phase 0: read kq1 ahead, compute kq0, refill P0
    half8 b0 = Ab[(2 + cr) * 128 + abase];
    half8 b1 = Ab[(2 + cr) * 128 + abase + 32];
    SM(P[0][0], P[0][1], a0, a1);
    P[0][0] = pP0[0]; P[0][1] = pP0[32]; pP0 += PB;
    // phase 1: read kq2 ahead, compute kq1, refill P1
    a0 = Ab[(4 + cr) * 128 + abase];
    a1 = Ab[(4 + cr) * 128 + abase + 32];
    SM(P[1][0], P[1][1], b0, b1);
    P[1][0] = pP1[0]; P[1][1] = pP1[32]; pP1 += PB;
    // phase 2: read kq3 ahead, compute kq2, refill P2
    b0 = Ab[(6 + cr) * 128 + abase];
    b1 = Ab[(6 + cr) * 128 + abase + 32];
    SM(P[2][0], P[2][1], a0, a1);
    P[2][0] = pP2[0]; P[2][1] = pP2[32]; pP2 += PB;
    // phase 3: compute kq3, refill P3
    SM(P[3][0], P[3][1], b0, b1);
    P[3][0] = pP3[0]; P[3][1] = pP3[32]; pP3 += PB;
  };

  // ---- prologue: stage rounds 0,1 (slabs 0,1); load P rounds 0,1 ----
  STAGE(0, 8192);
  STAGE(1, 8192);
  Pev[0][0] = pP0[0]; Pev[0][1] = pP0[32]; pP0 += 8 * HW_;
  Pev[1][0] = pP1[0]; Pev[1][1] = pP1[32]; pP1 += 8 * HW_;
  Pev[2][0] = pP2[0]; Pev[2][1] = pP2[32]; pP2 += 8 * HW_;
  Pev[3][0] = pP3[0]; Pev[3][1] = pP3[32]; pP3 += 8 * HW_;
  Pod[0][0] = pP0[0]; Pod[0][1] = pP0[32]; pP0 += 8 * HW_;
  Pod[1][0] = pP1[0]; Pod[1][1] = pP1[32]; pP1 += 8 * HW_;
  Pod[2][0] = pP2[0]; Pod[2][1] = pP2[32]; pP2 += 8 * HW_;
  Pod[3][0] = pP3[0]; Pod[3][1] = pP3[32]; pP3 += 8 * HW_;
  // pointers now at round 2 (stage and P)

  // ---- main loop: 4 rounds per iter; barrier+vmcnt every 2 rounds ----
#pragma unroll 1
  for (int g = 0; g < 8; ++g) {
    int rd = g * 4;
    // rounds rd, rd+1 (slabs 0,1); stage rd+2, rd+3 (slabs 2,3)
    asm volatile("s_waitcnt vmcnt(0)" ::: "memory");   // 2-round-old loads
    __builtin_amdgcn_s_barrier();                      // all waves past rd-1
    {
      int sb2 = (rd + 2 < 31) ? 8192 : 0;
      int sb3 = (rd + 3 < 31) ? 8192 : 0;
      int pb2 = (rd + 2 < 31) ? 8 * HW_ : 0;
      int pb3 = (rd + 3 < 31) ? 8 * HW_ : 0;
      STAGE(2, sb2);
      STAGE(3, sb3);
      COMP(&A_lds[0][0], Pev, pb2);
      COMP(&A_lds[1][0], Pod, pb3);
    }
    // rounds rd+2, rd+3 (slabs 2,3); stage rd+4, rd+5 (slabs 0,1)
    asm volatile("s_waitcnt vmcnt(0)" ::: "memory");
    __builtin_amdgcn_s_barrier();
    {
      int sb4 = (rd + 4 < 31) ? 8192 : 0;
      int sb5 = (rd + 5 < 31) ? 8192 : 0;
      int pb4 = (rd + 4 < 31) ? 8 * HW_ : 0;
      int pb5 = (rd + 5 < 31) ? 8 * HW_ : 0;
      STAGE(0, sb4);
      STAGE(1, sb5);
      COMP(&A_lds[2][0], Pev, pb4);
      COMP(&A_lds[3][0], Pod, pb5);
    }
  }

  // ---- epilogue: 32x32 C/D layout col=lane&31, row=(reg&3)+8*(reg>>2)+4*cr ----
  size_t obase = (size_t)b * 256 * HW_ + colb;
#pragma unroll
  for (int reg = 0; reg < 16; ++reg) {
    int row = o0 + wr * 64 + (reg & 3) + 8 * (reg >> 2) + 4 * cr;
    out[obase + (size_t)row * HW_]                    = acc00[reg];
    out[obase + (size_t)row * HW_ + 32]               = acc01[reg];
    out[obase + (size_t)(row + 32) * HW_]             = acc10[reg];
    out[obase + (size_t)(row + 32) * HW_ + 32]        = acc11[reg];
  }
}

extern "C" void kernel_launch(void* const* d_in, const int* in_sizes, int n_in,
                              void* d_out, int out_size, void* d_ws, size_t ws_size,
                              hipStream_t stream) {
  const float* mat0      = (const float*)d_in[0];   // [8,256,64,64]
  const float* mat1      = (const float*)d_in[1];   // [256,256,8]
  const float* mask      = (const float*)d_in[2];   // [8,64,64]
  const float* Alpha     = (const float*)d_in[3];   // [8]
  const int*   use_alpha = (const int*)d_in[4];     // [1]
  (void)in_sizes; (void)n_in; (void)out_size; (void)ws_size;

  _Float16* Aprep = (_Float16*)d_ws;                // 1 MiB scratch
  float* outp  = (float*)d_out;

  prep_w_kernel<<<256, 256, 0, stream>>>(mat1, Alpha, use_alpha, Aprep);
  gemm_deform_kernel<<<512, 256, 0, stream>>>(mat0, Aprep, mask, outp);
}